// Round 3
// baseline (290.230 us; speedup 1.0000x reference)
//
#include <hip/hip_runtime.h>
#include <hip/hip_bf16.h>

#define BATCH 8
#define CD 512
#define NT 4096
#define EPSV 1e-5f

using u16x8 = __attribute__((ext_vector_type(8))) unsigned short;
using u16x4 = __attribute__((ext_vector_type(4))) unsigned short;
using bf8   = __attribute__((ext_vector_type(8))) short;
using f32x4 = __attribute__((ext_vector_type(4))) float;

__device__ __forceinline__ float b2f(unsigned short u) {
    union { unsigned int i; float f; } x; x.i = ((unsigned int)u) << 16; return x.f;
}
__device__ __forceinline__ unsigned short f2b(float f) {
    unsigned int x = __float_as_uint(f);
    unsigned int r = (x + 0x7fffu + ((x >> 16) & 1u)) >> 16;
    return (unsigned short)r;
}
__device__ __forceinline__ void gload_lds16(const void* g, void* l) {
    __builtin_amdgcn_global_load_lds((const __attribute__((address_space(1))) unsigned int*)g,
                                     (__attribute__((address_space(3))) unsigned int*)l, 16, 0, 0);
}

// ---------- W fp32 -> bf16 (row-major kept) ----------
__global__ __launch_bounds__(256)
void wconv(const float* __restrict__ W0, const float* __restrict__ W1,
           const float* __restrict__ W2, const float* __restrict__ W3,
           unsigned short* __restrict__ Wb) {
    const float* src = (blockIdx.y == 0) ? W0 : (blockIdx.y == 1) ? W1 : (blockIdx.y == 2) ? W2 : W3;
    unsigned short* dst = Wb + (size_t)blockIdx.y * CD * CD;
    const int base = blockIdx.x * 4096 + threadIdx.x * 16;
    u16x8 o0, o1;
    #pragma unroll
    for (int i = 0; i < 4; ++i) {
        float4 v = *reinterpret_cast<const float4*>(src + base + i * 4);
        unsigned short* t = (i < 2) ? (unsigned short*)&o0 : (unsigned short*)&o1;
        t[(i & 1) * 4 + 0] = f2b(v.x); t[(i & 1) * 4 + 1] = f2b(v.y);
        t[(i & 1) * 4 + 2] = f2b(v.z); t[(i & 1) * 4 + 3] = f2b(v.w);
    }
    *(u16x8*)(dst + base)     = o0;
    *(u16x8*)(dst + base + 8) = o1;
}

// ---------- fused projection GEMM ----------
// T[b][n][d] = act( sum_c X[b][c][n] * W[d][c] ), X f32 c-major, W bf16 row-major,
// T bf16 token-major. A-operand (X^T) staged via reg transpose+convert; B via global_load_lds.
template<int ACT>
__global__ __launch_bounds__(256)
void proj_gemm(const float* __restrict__ X, const unsigned short* __restrict__ W,
               unsigned short* __restrict__ T) {
    __shared__ __align__(16) unsigned short Xs[128 * 64];  // [n][c], XOR-swizzled
    __shared__ __align__(16) unsigned short Ws[128 * 64];  // [d][c], XOR-swizzled
    const int b  = blockIdx.z;
    const int n0 = blockIdx.y * 128;
    const int d0 = blockIdx.x * 128;
    const float* Xb = X + (size_t)b * CD * NT;
    unsigned short* Tb = T + (size_t)b * NT * CD;
    const int tid = threadIdx.x;
    const int lane = tid & 63;
    const int wv = tid >> 6, wi = wv >> 1, wj = wv & 1;

    f32x4 acc[4][4];
    #pragma unroll
    for (int m = 0; m < 4; ++m)
        #pragma unroll
        for (int j = 0; j < 4; ++j)
            acc[m][j] = (f32x4){0.f, 0.f, 0.f, 0.f};

    for (int k0 = 0; k0 < CD; k0 += 64) {
        // --- Ws: 128 d-rows x 64 c, global_load_lds with pre-swizzled source ---
        #pragma unroll
        for (int it = 0; it < 4; ++it) {
            const int idx = it * 256 + tid;
            const int r = idx >> 3, p = idx & 7;
            const int ps = p ^ (r & 7);
            gload_lds16(W + (size_t)(d0 + r) * CD + k0 + ps * 8, (char*)Ws + idx * 16);
        }
        // --- Xs: 64 c-rows x 128 n f32 -> transposed bf16 [n][c], swizzled ds_write_b64 ---
        #pragma unroll
        for (int sb = 0; sb < 2; ++sb) {
            const int s  = sb * 256 + tid;
            const int cq = s >> 5;          // 0..15 (c quad)
            const int nq = s & 31;          // 0..31 (n quad)
            float va[4][4];
            #pragma unroll
            for (int e = 0; e < 4; ++e) {
                float4 v = *reinterpret_cast<const float4*>(
                    Xb + (size_t)(k0 + cq * 4 + e) * NT + n0 + nq * 4);
                va[e][0] = v.x; va[e][1] = v.y; va[e][2] = v.z; va[e][3] = v.w;
            }
            #pragma unroll
            for (int j = 0; j < 4; ++j) {
                const int row = nq * 4 + j;
                u16x4 h;
                h[0] = f2b(va[0][j]); h[1] = f2b(va[1][j]);
                h[2] = f2b(va[2][j]); h[3] = f2b(va[3][j]);
                const int byte = (row * 128 + cq * 8) ^ ((row & 7) << 4);
                *(u16x4*)((char*)Xs + byte) = h;
            }
        }
        __syncthreads();
        #pragma unroll
        for (int kk = 0; kk < 2; ++kk) {
            bf8 af[4], bfr[4];
            #pragma unroll
            for (int m = 0; m < 4; ++m) {
                const int r  = wi * 64 + m * 16 + (lane & 15);
                const int kp = kk * 4 + (lane >> 4);
                af[m] = *(const bf8*)((const char*)Xs + r * 128 + ((kp ^ (r & 7)) * 16));
            }
            #pragma unroll
            for (int j = 0; j < 4; ++j) {
                const int r  = wj * 64 + j * 16 + (lane & 15);
                const int kp = kk * 4 + (lane >> 4);
                bfr[j] = *(const bf8*)((const char*)Ws + r * 128 + ((kp ^ (r & 7)) * 16));
            }
            #pragma unroll
            for (int m = 0; m < 4; ++m)
                #pragma unroll
                for (int j = 0; j < 4; ++j)
                    acc[m][j] = __builtin_amdgcn_mfma_f32_16x16x32_bf16(af[m], bfr[j], acc[m][j], 0, 0, 0);
        }
        __syncthreads();
    }

    #pragma unroll
    for (int m = 0; m < 4; ++m) {
        const int ib = n0 + wi * 64 + m * 16 + (lane >> 4) * 4;   // token row
        #pragma unroll
        for (int j = 0; j < 4; ++j) {
            const int jb = d0 + wj * 64 + j * 16 + (lane & 15);   // d col
            f32x4 v = acc[m][j];
            #pragma unroll
            for (int r = 0; r < 4; ++r) {
                float val = v[r];
                if (ACT) val = (val > 0.f) ? (val + 1.f) : __expf(val);
                Tb[(size_t)(ib + r) * CD + jb] = f2b(val);
            }
        }
    }
}

// ---------- NT-GEMM (bf16 x bf16): D[i][j] = sum_k A[i][k]*B[j][k] ----------
template<int ACT, int OUTF32>
__global__ __launch_bounds__(256)
void gemm_rr(const unsigned short* __restrict__ A, long aBatch,
             const unsigned short* __restrict__ B, long bBatch,
             void* __restrict__ Out, const float* __restrict__ bias, int N) {
    __shared__ __align__(16) unsigned short Asm[128 * 64];
    __shared__ __align__(16) unsigned short Bsm[128 * 64];
    const int b  = blockIdx.z;
    const int i0 = blockIdx.y * 128;
    const int j0 = blockIdx.x * 128;
    const unsigned short* Ab = A + (size_t)b * aBatch;
    const unsigned short* Bb = B + (size_t)b * bBatch;
    const int tid  = threadIdx.x;
    const int lane = tid & 63;
    const int wv   = tid >> 6;
    const int wi = wv >> 1, wj = wv & 1;

    f32x4 acc[4][4];
    #pragma unroll
    for (int m = 0; m < 4; ++m)
        #pragma unroll
        for (int j = 0; j < 4; ++j)
            acc[m][j] = (f32x4){0.f, 0.f, 0.f, 0.f};

    for (int k0 = 0; k0 < CD; k0 += 64) {
        #pragma unroll
        for (int it = 0; it < 4; ++it) {
            const int idx = it * 256 + tid;
            const int r = idx >> 3, p = idx & 7;
            const int ps = p ^ (r & 7);
            gload_lds16(Ab + (size_t)(i0 + r) * CD + k0 + ps * 8, (char*)Asm + idx * 16);
            gload_lds16(Bb + (size_t)(j0 + r) * CD + k0 + ps * 8, (char*)Bsm + idx * 16);
        }
        __syncthreads();
        #pragma unroll
        for (int kk = 0; kk < 2; ++kk) {
            bf8 af[4], bfr[4];
            #pragma unroll
            for (int m = 0; m < 4; ++m) {
                const int r  = wi * 64 + m * 16 + (lane & 15);
                const int kp = kk * 4 + (lane >> 4);
                af[m] = *(const bf8*)((const char*)Asm + r * 128 + ((kp ^ (r & 7)) * 16));
            }
            #pragma unroll
            for (int j = 0; j < 4; ++j) {
                const int r  = wj * 64 + j * 16 + (lane & 15);
                const int kp = kk * 4 + (lane >> 4);
                bfr[j] = *(const bf8*)((const char*)Bsm + r * 128 + ((kp ^ (r & 7)) * 16));
            }
            #pragma unroll
            for (int m = 0; m < 4; ++m)
                #pragma unroll
                for (int j = 0; j < 4; ++j)
                    acc[m][j] = __builtin_amdgcn_mfma_f32_16x16x32_bf16(af[m], bfr[j], acc[m][j], 0, 0, 0);
        }
        __syncthreads();
    }

    const size_t oBatch = (size_t)NT * CD;
    #pragma unroll
    for (int m = 0; m < 4; ++m) {
        const int ib = i0 + wi * 64 + m * 16 + (lane >> 4) * 4;
        #pragma unroll
        for (int j = 0; j < 4; ++j) {
            const int jb = j0 + wj * 64 + j * 16 + (lane & 15);
            f32x4 v = acc[m][j];
            #pragma unroll
            for (int r = 0; r < 4; ++r) {
                float val = v[r];
                if (ACT) val = (val > 0.f) ? (val + 1.f) : __expf(val);
                if (OUTF32) {
                    ((float*)Out)[(size_t)b * oBatch + (size_t)(ib + r) * N + jb] = val + bias[ib + r];
                } else {
                    ((unsigned short*)Out)[(size_t)b * oBatch + (size_t)(ib + r) * N + jb] = f2b(val);
                }
            }
        }
    }
}

// ---------- Ksum[b][c] = sum_n K[b][n][c]  (2-pass, deterministic) ----------
__global__ __launch_bounds__(256)
void ksum_part(const unsigned short* __restrict__ K, float* __restrict__ part) {
    const int b = blockIdx.y, ch = blockIdx.x, t = threadIdx.x;
    const unsigned short* base = K + ((size_t)b * NT + ch * 256) * CD;
    float a0 = 0.f, a1 = 0.f;
    for (int nn = 0; nn < 256; ++nn) {
        a0 += b2f(base[(size_t)nn * CD + t]);
        a1 += b2f(base[(size_t)nn * CD + 256 + t]);
    }
    float* p = part + (size_t)(b * 16 + ch) * CD;
    p[t] = a0; p[256 + t] = a1;
}
__global__ __launch_bounds__(512)
void ksum_red(const float* __restrict__ part, float* __restrict__ Ks) {
    const int b = blockIdx.x, c = threadIdx.x;
    float s = 0.f;
    #pragma unroll
    for (int i = 0; i < 16; ++i) s += part[(size_t)(b * 16 + i) * CD + c];
    Ks[b * CD + c] = s;
}

// ---------- middle: S = Q K^T (per token), Z, out = Z * S V ; token-major bf16 ----------
__global__ __launch_bounds__(256)
void middle(const unsigned short* __restrict__ Q, const unsigned short* __restrict__ K,
            const unsigned short* __restrict__ V, const float* __restrict__ Ksum,
            unsigned short* __restrict__ T) {
    __shared__ __align__(16) unsigned short sK[16][520];
    __shared__ __align__(16) unsigned short sV[16][520];
    const int b  = blockIdx.y;
    const int n0 = blockIdx.x * 16;
    const int tid = threadIdx.x;
    const int lane = tid & 63, wv = tid >> 6;
    const size_t rowbase = (size_t)b * NT + n0;

    #pragma unroll
    for (int i = 0; i < 4; ++i) {
        const int row = wv * 4 + i;
        gload_lds16(K + (rowbase + row) * CD + lane * 8, (char*)&sK[row][0] + lane * 16);
        gload_lds16(V + (rowbase + row) * CD + lane * 8, (char*)&sV[row][0] + lane * 16);
    }
    __syncthreads();

    const int tok = tid >> 4, h = tid & 15;
    const unsigned short* qp = Q + (rowbase + tok) * CD + h * 32;
    float q[32];
    #pragma unroll
    for (int i = 0; i < 4; ++i) {
        u16x8 u = *(const u16x8*)(qp + i * 8);
        #pragma unroll
        for (int e = 0; e < 8; ++e) q[i * 8 + e] = b2f(u[e]);
    }

    float S[16];
    #pragma unroll
    for (int hp = 0; hp < 16; ++hp) {
        float s = 0.f;
        #pragma unroll
        for (int i = 0; i < 4; ++i) {
            u16x8 u = *(const u16x8*)(&sK[tok][hp * 32 + i * 8]);
            #pragma unroll
            for (int e = 0; e < 8; ++e) s += q[i * 8 + e] * b2f(u[e]);
        }
        S[hp] = s;
    }

    const float* ks = Ksum + b * CD + h * 32;
    float zden = EPSV;
    #pragma unroll
    for (int i = 0; i < 8; ++i) {
        float4 kv = *reinterpret_cast<const float4*>(ks + i * 4);
        zden += q[i * 4 + 0] * kv.x + q[i * 4 + 1] * kv.y + q[i * 4 + 2] * kv.z + q[i * 4 + 3] * kv.w;
    }
    const float z = 1.f / zden;

    float o[32] = {};
    #pragma unroll
    for (int hp = 0; hp < 16; ++hp) {
        const float s = S[hp];
        #pragma unroll
        for (int i = 0; i < 4; ++i) {
            u16x8 u = *(const u16x8*)(&sV[tok][hp * 32 + i * 8]);
            #pragma unroll
            for (int e = 0; e < 8; ++e) o[i * 8 + e] += s * b2f(u[e]);
        }
    }

    unsigned short* tp = T + (rowbase + tok) * CD + h * 32;
    #pragma unroll
    for (int i = 0; i < 4; ++i) {
        u16x8 u;
        #pragma unroll
        for (int e = 0; e < 8; ++e) u[e] = f2b(o[i * 8 + e] * z);
        *(u16x8*)(tp + i * 8) = u;
    }
}

// ---------- launch ----------
extern "C" void kernel_launch(void* const* d_in, const int* in_sizes, int n_in,
                              void* d_out, int out_size, void* d_ws, size_t ws_size,
                              hipStream_t stream) {
    const float* q  = (const float*)d_in[0];
    const float* k  = (const float*)d_in[1];
    const float* v  = (const float*)d_in[2];
    const float* Wq = (const float*)d_in[3];
    const float* Wk = (const float*)d_in[4];
    const float* Wv = (const float*)d_in[5];
    const float* Wp = (const float*)d_in[6];
    const float* bp = (const float*)d_in[7];
    float* out = (float*)d_out;

    const size_t slab = (size_t)BATCH * NT * CD;
    const long   perB = (long)NT * CD;
    unsigned short* Qp = (unsigned short*)d_ws;       // Q projected (token-major)
    unsigned short* Kp = Qp + slab;                   // K projected
    unsigned short* Vp = Kp + slab;                   // V projected
    unsigned short* Tm = Vp + slab;                   // middle output
    unsigned short* Wb = Tm + slab;                   // 4 x 512x512 bf16
    float* Kpart = (float*)(Wb + 4 * (size_t)CD * CD);
    float* Ks    = Kpart + 8 * 16 * CD;

    wconv<<<dim3(64, 4), 256, 0, stream>>>(Wq, Wk, Wv, Wp, Wb);

    const unsigned short* Wqb = Wb;
    const unsigned short* Wkb = Wb + (size_t)CD * CD;
    const unsigned short* Wvb = Wb + (size_t)2 * CD * CD;
    const unsigned short* Wpb = Wb + (size_t)3 * CD * CD;

    dim3 gp(4, 32, 8);   // d-tiles, n-tiles, batch
    proj_gemm<1><<<gp, 256, 0, stream>>>(q, Wqb, Qp);
    proj_gemm<1><<<gp, 256, 0, stream>>>(k, Wkb, Kp);
    proj_gemm<0><<<gp, 256, 0, stream>>>(v, Wvb, Vp);

    ksum_part<<<dim3(16, 8), 256, 0, stream>>>(Kp, Kpart);
    ksum_red <<<dim3(8),     512, 0, stream>>>(Kpart, Ks);

    middle<<<dim3(256, 8), 256, 0, stream>>>(Qp, Kp, Vp, Ks, Tm);

    gemm_rr<0, 1><<<dim3(32, 4, 8), 256, 0, stream>>>(Wpb, 0, Tm, perB, out, bp, NT);
}

// Round 5
// 236.434 us; speedup vs baseline: 1.2275x; 1.2275x over previous
//
#include <hip/hip_runtime.h>
#include <hip/hip_bf16.h>

#define BATCH 8
#define CD 512
#define NT 4096
#define EPSV 1e-5f

using u16x8 = __attribute__((ext_vector_type(8))) unsigned short;
using u16x4 = __attribute__((ext_vector_type(4))) unsigned short;
using bf8   = __attribute__((ext_vector_type(8))) short;
using f32x4 = __attribute__((ext_vector_type(4))) float;

__device__ __forceinline__ float b2f(unsigned short u) {
    union { unsigned int i; float f; } x; x.i = ((unsigned int)u) << 16; return x.f;
}
__device__ __forceinline__ unsigned short f2b(float f) {
    unsigned int x = __float_as_uint(f);
    unsigned int r = (x + 0x7fffu + ((x >> 16) & 1u)) >> 16;
    return (unsigned short)r;
}
__device__ __forceinline__ void gload_lds16(const void* g, void* l) {
    __builtin_amdgcn_global_load_lds((const __attribute__((address_space(1))) unsigned int*)g,
                                     (__attribute__((address_space(3))) unsigned int*)l, 16, 0, 0);
}

// ---------- W fp32 -> bf16 (row-major kept) ----------
__global__ __launch_bounds__(256)
void wconv(const float* __restrict__ W0, const float* __restrict__ W1,
           const float* __restrict__ W2, const float* __restrict__ W3,
           unsigned short* __restrict__ Wb) {
    const float* src = (blockIdx.y == 0) ? W0 : (blockIdx.y == 1) ? W1 : (blockIdx.y == 2) ? W2 : W3;
    unsigned short* dst = Wb + (size_t)blockIdx.y * CD * CD;
    const int base = blockIdx.x * 4096 + threadIdx.x * 16;
    u16x8 o0, o1;
    #pragma unroll
    for (int i = 0; i < 4; ++i) {
        float4 v = *reinterpret_cast<const float4*>(src + base + i * 4);
        unsigned short* t = (i < 2) ? (unsigned short*)&o0 : (unsigned short*)&o1;
        t[(i & 1) * 4 + 0] = f2b(v.x); t[(i & 1) * 4 + 1] = f2b(v.y);
        t[(i & 1) * 4 + 2] = f2b(v.z); t[(i & 1) * 4 + 3] = f2b(v.w);
    }
    *(u16x8*)(dst + base)     = o0;
    *(u16x8*)(dst + base + 8) = o1;
}

// ---------- fused projection GEMM (XCD-chunked swizzle, d-tile fastest) ----------
// T[b][n][d] = act( sum_c X[b][c][n] * W[d][c] )
template<int ACT>
__global__ __launch_bounds__(256)
void proj_gemm(const float* __restrict__ X, const unsigned short* __restrict__ W,
               unsigned short* __restrict__ T) {
    __shared__ __align__(16) unsigned short Xs[128 * 64];
    __shared__ __align__(16) unsigned short Ws[128 * 64];
    const int nper = gridDim.x >> 3;
    const int work = (blockIdx.x & 7) * nper + (blockIdx.x >> 3);
    const int d0 = (work & 3) * 128;
    const int n0 = ((work >> 2) & 31) * 128;
    const int b  = work >> 7;
    const float* Xb = X + (size_t)b * CD * NT;
    unsigned short* Tb = T + (size_t)b * NT * CD;
    const int tid = threadIdx.x;
    const int lane = tid & 63;
    const int wv = tid >> 6, wi = wv >> 1, wj = wv & 1;

    f32x4 acc[4][4];
    #pragma unroll
    for (int m = 0; m < 4; ++m)
        #pragma unroll
        for (int j = 0; j < 4; ++j)
            acc[m][j] = (f32x4){0.f, 0.f, 0.f, 0.f};

    for (int k0 = 0; k0 < CD; k0 += 64) {
        #pragma unroll
        for (int it = 0; it < 4; ++it) {
            const int idx = it * 256 + tid;
            const int r = idx >> 3, p = idx & 7;
            const int ps = p ^ (r & 7);
            gload_lds16(W + (size_t)(d0 + r) * CD + k0 + ps * 8, (char*)Ws + idx * 16);
        }
        #pragma unroll
        for (int sb = 0; sb < 2; ++sb) {
            const int s  = sb * 256 + tid;
            const int cq = s >> 5;
            const int nq = s & 31;
            float va[4][4];
            #pragma unroll
            for (int e = 0; e < 4; ++e) {
                float4 v = *reinterpret_cast<const float4*>(
                    Xb + (size_t)(k0 + cq * 4 + e) * NT + n0 + nq * 4);
                va[e][0] = v.x; va[e][1] = v.y; va[e][2] = v.z; va[e][3] = v.w;
            }
            #pragma unroll
            for (int j = 0; j < 4; ++j) {
                const int row = nq * 4 + j;
                u16x4 h;
                h[0] = f2b(va[0][j]); h[1] = f2b(va[1][j]);
                h[2] = f2b(va[2][j]); h[3] = f2b(va[3][j]);
                const int byte = (row * 128 + cq * 8) ^ ((row & 7) << 4);
                *(u16x4*)((char*)Xs + byte) = h;
            }
        }
        __syncthreads();
        #pragma unroll
        for (int kk = 0; kk < 2; ++kk) {
            bf8 af[4], bfr[4];
            #pragma unroll
            for (int m = 0; m < 4; ++m) {
                const int r  = wi * 64 + m * 16 + (lane & 15);
                const int kp = kk * 4 + (lane >> 4);
                af[m] = *(const bf8*)((const char*)Xs + r * 128 + ((kp ^ (r & 7)) * 16));
            }
            #pragma unroll
            for (int j = 0; j < 4; ++j) {
                const int r  = wj * 64 + j * 16 + (lane & 15);
                const int kp = kk * 4 + (lane >> 4);
                bfr[j] = *(const bf8*)((const char*)Ws + r * 128 + ((kp ^ (r & 7)) * 16));
            }
            #pragma unroll
            for (int m = 0; m < 4; ++m)
                #pragma unroll
                for (int j = 0; j < 4; ++j)
                    acc[m][j] = __builtin_amdgcn_mfma_f32_16x16x32_bf16(af[m], bfr[j], acc[m][j], 0, 0, 0);
        }
        __syncthreads();
    }

    #pragma unroll
    for (int m = 0; m < 4; ++m) {
        const int ib = n0 + wi * 64 + m * 16 + (lane >> 4) * 4;
        #pragma unroll
        for (int j = 0; j < 4; ++j) {
            const int jb = d0 + wj * 64 + j * 16 + (lane & 15);
            f32x4 v = acc[m][j];
            #pragma unroll
            for (int r = 0; r < 4; ++r) {
                float val = v[r];
                if (ACT) val = (val > 0.f) ? (val + 1.f) : __expf(val);
                Tb[(size_t)(ib + r) * CD + jb] = f2b(val);
            }
        }
    }
}

// ---------- final GEMM: out[b][d][n] = sum_c Wp[d][c]*Tm[b][n][c] + bias[d] ----------
__global__ __launch_bounds__(256)
void gemm_final(const unsigned short* __restrict__ Wp, const unsigned short* __restrict__ Tm,
                float* __restrict__ out, const float* __restrict__ bias) {
    __shared__ __align__(16) unsigned short Asm[128 * 64];
    __shared__ __align__(16) unsigned short Bsm[128 * 64];
    const int nper = gridDim.x >> 3;
    const int work = (blockIdx.x & 7) * nper + (blockIdx.x >> 3);
    const int i0 = (work & 3) * 128;             // d tile (fastest -> shares Tm panel)
    const int j0 = ((work >> 2) & 31) * 128;     // token tile
    const int b  = work >> 7;
    const unsigned short* Bb = Tm + (size_t)b * NT * CD;
    const int tid  = threadIdx.x;
    const int lane = tid & 63;
    const int wv   = tid >> 6;
    const int wi = wv >> 1, wj = wv & 1;

    f32x4 acc[4][4];
    #pragma unroll
    for (int m = 0; m < 4; ++m)
        #pragma unroll
        for (int j = 0; j < 4; ++j)
            acc[m][j] = (f32x4){0.f, 0.f, 0.f, 0.f};

    for (int k0 = 0; k0 < CD; k0 += 64) {
        #pragma unroll
        for (int it = 0; it < 4; ++it) {
            const int idx = it * 256 + tid;
            const int r = idx >> 3, p = idx & 7;
            const int ps = p ^ (r & 7);
            gload_lds16(Wp + (size_t)(i0 + r) * CD + k0 + ps * 8, (char*)Asm + idx * 16);
            gload_lds16(Bb + (size_t)(j0 + r) * CD + k0 + ps * 8, (char*)Bsm + idx * 16);
        }
        __syncthreads();
        #pragma unroll
        for (int kk = 0; kk < 2; ++kk) {
            bf8 af[4], bfr[4];
            #pragma unroll
            for (int m = 0; m < 4; ++m) {
                const int r  = wi * 64 + m * 16 + (lane & 15);
                const int kp = kk * 4 + (lane >> 4);
                af[m] = *(const bf8*)((const char*)Asm + r * 128 + ((kp ^ (r & 7)) * 16));
            }
            #pragma unroll
            for (int j = 0; j < 4; ++j) {
                const int r  = wj * 64 + j * 16 + (lane & 15);
                const int kp = kk * 4 + (lane >> 4);
                bfr[j] = *(const bf8*)((const char*)Bsm + r * 128 + ((kp ^ (r & 7)) * 16));
            }
            #pragma unroll
            for (int m = 0; m < 4; ++m)
                #pragma unroll
                for (int j = 0; j < 4; ++j)
                    acc[m][j] = __builtin_amdgcn_mfma_f32_16x16x32_bf16(af[m], bfr[j], acc[m][j], 0, 0, 0);
        }
        __syncthreads();
    }

    #pragma unroll
    for (int m = 0; m < 4; ++m) {
        const int ib = i0 + wi * 64 + m * 16 + (lane >> 4) * 4;
        #pragma unroll
        for (int j = 0; j < 4; ++j) {
            const int jb = j0 + wj * 64 + j * 16 + (lane & 15);
            f32x4 v = acc[m][j];
            #pragma unroll
            for (int r = 0; r < 4; ++r)
                out[(size_t)b * CD * NT + (size_t)(ib + r) * NT + jb] = v[r] + bias[ib + r];
        }
    }
}

// ---------- Ksum[b][c] = sum_n K[b][n][c]  (2-pass, deterministic) ----------
__global__ __launch_bounds__(256)
void ksum_part(const unsigned short* __restrict__ K, float* __restrict__ part) {
    const int b = blockIdx.y, ch = blockIdx.x, t = threadIdx.x;
    const unsigned short* base = K + ((size_t)b * NT + ch * 256) * CD;
    float a0 = 0.f, a1 = 0.f;
    for (int nn = 0; nn < 256; ++nn) {
        a0 += b2f(base[(size_t)nn * CD + t]);
        a1 += b2f(base[(size_t)nn * CD + 256 + t]);
    }
    float* p = part + (size_t)(b * 16 + ch) * CD;
    p[t] = a0; p[256 + t] = a1;
}
__global__ __launch_bounds__(512)
void ksum_red(const float* __restrict__ part, float* __restrict__ Ks) {
    const int b = blockIdx.x, c = threadIdx.x;
    float s = 0.f;
    #pragma unroll
    for (int i = 0; i < 16; ++i) s += part[(size_t)(b * 16 + i) * CD + c];
    Ks[b * CD + c] = s;
}

// ---------- middle (MFMA, builtins only) ----------
// Per token (1 wave, 4 tokens/wave):
//   S^T[h'][h] = mfma_16x16x32(A=K-frag, B=Q-frag)        (contract d=32)
//   z[h] = 1/(Q[h]·Ksum[h]+eps)                            (8 FMA + 2 shfl)
//   P = z*S^T -> bf16 -> per-wave LDS tile sP[h][h'] (cols 16..31 zeroed)
//   out^T[m][h] = mfma_16x16x32(A=V^T-frag (k=h', zero-padded 16..31), B=P-frag)
__global__ __launch_bounds__(256)
void middle2(const unsigned short* __restrict__ Q, const unsigned short* __restrict__ K,
             const unsigned short* __restrict__ V, const float* __restrict__ Ksum,
             unsigned short* __restrict__ T) {
    __shared__ __align__(16) unsigned short sV[4][512];      // per-wave V token row
    __shared__ __align__(16) unsigned short sP[4][16][32];   // per-wave P^T [h][h'], h'=16..31 zero
    const int b = blockIdx.y;
    const int tid = threadIdx.x;
    const int w = tid >> 6, lane = tid & 63;
    const int r16 = lane & 15, g = lane >> 4;
    const int n0 = blockIdx.x * 16 + w * 4;
    const unsigned short* Qb = Q + ((size_t)b * NT + n0) * CD;
    const unsigned short* Kb = K + ((size_t)b * NT + n0) * CD;
    const unsigned short* Vb = V + ((size_t)b * NT + n0) * CD;
    unsigned short* Tb = T + ((size_t)b * NT + n0) * CD;
    const int fragoff = r16 * 32 + g * 8;   // head h=r16, d=g*8..g*8+7

    // zero the pad half of this wave's sP (16 rows x cols 16..31)
    {
        const int r = lane >> 2, cq = lane & 3;
        *(u16x4*)&sP[w][r][16 + cq * 4] = (u16x4){0, 0, 0, 0};
    }

    // Ksum fragment (matches Q B-frag: h=r16, d=g*8..+7)
    const float* ksp = Ksum + b * CD + fragoff;
    float ks[8];
    {
        float4 a0 = *(const float4*)ksp;
        float4 a1 = *(const float4*)(ksp + 4);
        ks[0] = a0.x; ks[1] = a0.y; ks[2] = a0.z; ks[3] = a0.w;
        ks[4] = a1.x; ks[5] = a1.y; ks[6] = a1.z; ks[7] = a1.w;
    }
    unsigned short* sVw = &sV[w][0];

    for (int t = 0; t < 4; ++t) {
        // prior iteration's LDS reads must retire before overwriting wave buffers
        asm volatile("s_waitcnt lgkmcnt(0)" ::: "memory");
        __builtin_amdgcn_sched_barrier(0);
        gload_lds16(Vb + (size_t)t * CD + lane * 8, (char*)sVw + lane * 16);

        const bf8 qf = *(const bf8*)(Qb + (size_t)t * CD + fragoff);
        const bf8 kf = *(const bf8*)(Kb + (size_t)t * CD + fragoff);

        // S^T[h'][h]: A=K (row=h'), B=Q (col=h), contract d
        f32x4 s = {0.f, 0.f, 0.f, 0.f};
        s = __builtin_amdgcn_mfma_f32_16x16x32_bf16(kf, qf, s, 0, 0, 0);

        // z for h=r16 (lane-uniform within acc column)
        float part = 0.f;
        #pragma unroll
        for (int e = 0; e < 8; ++e) part += b2f((unsigned short)qf[e]) * ks[e];
        part += __shfl_xor(part, 16, 64);
        part += __shfl_xor(part, 32, 64);
        const float z = 1.f / (part + EPSV);

        // P write: acc lane holds col h=r16, rows h'=g*4+r -> sP[h][h']
        u16x4 pw;
        #pragma unroll
        for (int r = 0; r < 4; ++r) pw[r] = f2b(s[r] * z);
        *(u16x4*)&sP[w][r16][g * 4] = pw;

        // drain V stage (vm) and P write (lgkm) before LDS reads
        asm volatile("s_waitcnt vmcnt(0) lgkmcnt(0)" ::: "memory");
        __builtin_amdgcn_sched_barrier(0);

        // B-frag: P[k=h'][h]: lane (g,r16) reads sP[r16][g*8..+7] (zeros for g>=2)
        const bf8 pb = *(const bf8*)&sP[w][r16][g * 8];
        // A-frags: V^T[m][h']: row=m_local=r16, k=h'=g*8+e; zero for k>=16
        bf8 va0 = {}, va1 = {};
        if (g < 2) {
            #pragma unroll
            for (int e = 0; e < 8; ++e) {
                va0[e] = (short)sVw[(g * 8 + e) * 32 + r16];
                va1[e] = (short)sVw[(g * 8 + e) * 32 + 16 + r16];
            }
        }

        f32x4 o0 = {0.f, 0.f, 0.f, 0.f}, o1 = {0.f, 0.f, 0.f, 0.f};
        o0 = __builtin_amdgcn_mfma_f32_16x16x32_bf16(va0, pb, o0, 0, 0, 0);
        o1 = __builtin_amdgcn_mfma_f32_16x16x32_bf16(va1, pb, o1, 0, 0, 0);

        // store: acc lane holds col h=r16, rows m_local=g*4+r; c = h*32 + mh*16 + m_local
        u16x4 w0, w1;
        #pragma unroll
        for (int r = 0; r < 4; ++r) { w0[r] = f2b(o0[r]); w1[r] = f2b(o1[r]); }
        *(u16x4*)(Tb + (size_t)t * CD + r16 * 32 + g * 4)      = w0;
        *(u16x4*)(Tb + (size_t)t * CD + r16 * 32 + 16 + g * 4) = w1;
    }
}

// ---------- launch ----------
extern "C" void kernel_launch(void* const* d_in, const int* in_sizes, int n_in,
                              void* d_out, int out_size, void* d_ws, size_t ws_size,
                              hipStream_t stream) {
    const float* q  = (const float*)d_in[0];
    const float* k  = (const float*)d_in[1];
    const float* v  = (const float*)d_in[2];
    const float* Wq = (const float*)d_in[3];
    const float* Wk = (const float*)d_in[4];
    const float* Wv = (const float*)d_in[5];
    const float* Wp = (const float*)d_in[6];
    const float* bp = (const float*)d_in[7];
    float* out = (float*)d_out;

    const size_t slab = (size_t)BATCH * NT * CD;
    unsigned short* Qp = (unsigned short*)d_ws;
    unsigned short* Kp = Qp + slab;
    unsigned short* Vp = Kp + slab;
    unsigned short* Tm = Vp + slab;
    unsigned short* Wb = Tm + slab;
    float* Kpart = (float*)(Wb + 4 * (size_t)CD * CD);
    float* Ks    = Kpart + 8 * 16 * CD;

    wconv<<<dim3(64, 4), 256, 0, stream>>>(Wq, Wk, Wv, Wp, Wb);

    const unsigned short* Wqb = Wb;
    const unsigned short* Wkb = Wb + (size_t)CD * CD;
    const unsigned short* Wvb = Wb + (size_t)2 * CD * CD;
    const unsigned short* Wpb = Wb + (size_t)3 * CD * CD;

    proj_gemm<1><<<1024, 256, 0, stream>>>(q, Wqb, Qp);
    proj_gemm<1><<<1024, 256, 0, stream>>>(k, Wkb, Kp);
    proj_gemm<0><<<1024, 256, 0, stream>>>(v, Wvb, Vp);

    ksum_part<<<dim3(16, 8), 256, 0, stream>>>(Kp, Kpart);
    ksum_red <<<dim3(8),     512, 0, stream>>>(Kpart, Ks);

    middle2<<<dim3(256, 8), 256, 0, stream>>>(Qp, Kp, Vp, Ks, Tm);

    gemm_final<<<1024, 256, 0, stream>>>(Wpb, Tm, out, bp);
}

// Round 6
// 229.117 us; speedup vs baseline: 1.2667x; 1.0319x over previous
//
#include <hip/hip_runtime.h>
#include <hip/hip_bf16.h>

#define BATCH 8
#define CD 512
#define NT 4096
#define EPSV 1e-5f

using u16x8 = __attribute__((ext_vector_type(8))) unsigned short;
using u16x4 = __attribute__((ext_vector_type(4))) unsigned short;
using bf8   = __attribute__((ext_vector_type(8))) short;
using f32x4 = __attribute__((ext_vector_type(4))) float;

__device__ __forceinline__ float b2f(unsigned short u) {
    union { unsigned int i; float f; } x; x.i = ((unsigned int)u) << 16; return x.f;
}
__device__ __forceinline__ unsigned short f2b(float f) {
    unsigned int x = __float_as_uint(f);
    unsigned int r = (x + 0x7fffu + ((x >> 16) & 1u)) >> 16;
    return (unsigned short)r;
}
__device__ __forceinline__ unsigned int cvtpk(float a, float b) {
    unsigned int r;
    asm("v_cvt_pk_bf16_f32 %0, %1, %2" : "=v"(r) : "v"(a), "v"(b));
    return r;  // lo = bf16(a), hi = bf16(b)
}
__device__ __forceinline__ void gload_lds16(const void* g, void* l) {
    __builtin_amdgcn_global_load_lds((const __attribute__((address_space(1))) unsigned int*)g,
                                     (__attribute__((address_space(3))) unsigned int*)l, 16, 0, 0);
}
__device__ __forceinline__ int swz8(int r) { return (r ^ (r >> 3)) & 7; }

// ---------- W fp32 -> bf16 (row-major kept) ----------
__global__ __launch_bounds__(256)
void wconv(const float* __restrict__ W0, const float* __restrict__ W1,
           const float* __restrict__ W2, const float* __restrict__ W3,
           unsigned short* __restrict__ Wb) {
    const float* src = (blockIdx.y == 0) ? W0 : (blockIdx.y == 1) ? W1 : (blockIdx.y == 2) ? W2 : W3;
    unsigned short* dst = Wb + (size_t)blockIdx.y * CD * CD;
    const int base = blockIdx.x * 4096 + threadIdx.x * 16;
    u16x8 o0, o1;
    #pragma unroll
    for (int i = 0; i < 4; ++i) {
        float4 v = *reinterpret_cast<const float4*>(src + base + i * 4);
        unsigned short* t = (i < 2) ? (unsigned short*)&o0 : (unsigned short*)&o1;
        t[(i & 1) * 4 + 0] = f2b(v.x); t[(i & 1) * 4 + 1] = f2b(v.y);
        t[(i & 1) * 4 + 2] = f2b(v.z); t[(i & 1) * 4 + 3] = f2b(v.w);
    }
    *(u16x8*)(dst + base)     = o0;
    *(u16x8*)(dst + base + 8) = o1;
}

// ---------- fused projection GEMM, all 3 tensors in one dispatch ----------
// T[b][n][d] = act( sum_c X[b][c][n] * W[d][c] ); X f32 c-major, W bf16, T bf16 token-major.
// X^T staged via reg transpose + cvt_pk (prefetched/converted under the prior MFMA phase);
// W staged via global_load_lds with pre-swizzled source. Swizzle swz8 on both sides.
struct XB { uint2 pk[2][4]; };   // [sb][j] packed 4 bf16 (c-quad) per row j

__device__ __forceinline__ void loadX(const float* __restrict__ Xb, int k0, int n0, int tid, XB& o) {
    #pragma unroll
    for (int sb = 0; sb < 2; ++sb) {
        const int s = sb * 256 + tid;
        const int cq = s >> 5, nq = s & 31;
        const float* p = Xb + (size_t)(k0 + cq * 4) * NT + n0 + nq * 4;
        float4 t0 = *(const float4*)(p);
        float4 t1 = *(const float4*)(p + NT);
        float4 t2 = *(const float4*)(p + 2 * NT);
        float4 t3 = *(const float4*)(p + 3 * NT);
        float a0[4] = {t0.x, t0.y, t0.z, t0.w};
        float a1[4] = {t1.x, t1.y, t1.z, t1.w};
        float a2[4] = {t2.x, t2.y, t2.z, t2.w};
        float a3[4] = {t3.x, t3.y, t3.z, t3.w};
        #pragma unroll
        for (int j = 0; j < 4; ++j) {
            uint2 u;
            u.x = cvtpk(a0[j], a1[j]);   // c0,c1
            u.y = cvtpk(a2[j], a3[j]);   // c2,c3
            o.pk[sb][j] = u;
        }
    }
}
__device__ __forceinline__ void storeX(unsigned short* Xs, int tid, const XB& o) {
    #pragma unroll
    for (int sb = 0; sb < 2; ++sb) {
        const int s = sb * 256 + tid;
        const int cq = s >> 5, nq = s & 31;
        #pragma unroll
        for (int j = 0; j < 4; ++j) {
            const int row = nq * 4 + j;
            const int byte = (row * 128 + cq * 8) ^ (swz8(row) << 4);
            *(uint2*)((char*)Xs + byte) = o.pk[sb][j];
        }
    }
}

__global__ __launch_bounds__(256)
void proj_gemm_all(const float* __restrict__ q, const float* __restrict__ k,
                   const float* __restrict__ v, const unsigned short* __restrict__ Wb,
                   unsigned short* __restrict__ Qp, unsigned short* __restrict__ Kp,
                   unsigned short* __restrict__ Vp) {
    __shared__ __align__(16) unsigned short Xs[128 * 64];
    __shared__ __align__(16) unsigned short Ws[128 * 64];
    const int nper = gridDim.x >> 3;                       // 384
    const int work = (blockIdx.x & 7) * nper + (blockIdx.x >> 3);
    const int mat = work >> 10;
    const int w2  = work & 1023;
    const int d0 = (w2 & 3) * 128;
    const int n0 = ((w2 >> 2) & 31) * 128;
    const int b  = w2 >> 7;
    const float* Xb = (mat == 0 ? q : mat == 1 ? k : v) + (size_t)b * CD * NT;
    const unsigned short* W = Wb + (size_t)mat * CD * CD;
    unsigned short* Tb = (mat == 0 ? Qp : mat == 1 ? Kp : Vp) + (size_t)b * NT * CD;
    const int act = (mat < 2);

    const int tid = threadIdx.x;
    const int lane = tid & 63;
    const int wv = tid >> 6, wi = wv >> 1, wj = wv & 1;

    f32x4 acc[4][4];
    #pragma unroll
    for (int m = 0; m < 4; ++m)
        #pragma unroll
        for (int j = 0; j < 4; ++j)
            acc[m][j] = (f32x4){0.f, 0.f, 0.f, 0.f};

    XB pa, pb;
    loadX(Xb, 0, n0, tid, pa);

    #pragma unroll
    for (int ks = 0; ks < 8; ++ks) {
        const int k0 = ks * 64;
        XB& cur = (ks & 1) ? pb : pa;
        XB& nxt = (ks & 1) ? pa : pb;
        // stage W (async, pre-swizzled source)
        #pragma unroll
        for (int it = 0; it < 4; ++it) {
            const int idx = it * 256 + tid;
            const int r = idx >> 3, p = idx & 7;
            gload_lds16(W + (size_t)(d0 + r) * CD + k0 + (p ^ swz8(r)) * 8, (char*)Ws + idx * 16);
        }
        storeX(Xs, tid, cur);
        __syncthreads();
        if (ks < 7) loadX(Xb, k0 + 64, n0, tid, nxt);   // flies + converts under MFMAs
        #pragma unroll
        for (int kk = 0; kk < 2; ++kk) {
            bf8 af[4], bfr[4];
            #pragma unroll
            for (int m = 0; m < 4; ++m) {
                const int r  = wi * 64 + m * 16 + (lane & 15);
                const int kp = kk * 4 + (lane >> 4);
                af[m] = *(const bf8*)((const char*)Xs + r * 128 + ((kp ^ swz8(r)) * 16));
            }
            #pragma unroll
            for (int j = 0; j < 4; ++j) {
                const int r  = wj * 64 + j * 16 + (lane & 15);
                const int kp = kk * 4 + (lane >> 4);
                bfr[j] = *(const bf8*)((const char*)Ws + r * 128 + ((kp ^ swz8(r)) * 16));
            }
            #pragma unroll
            for (int m = 0; m < 4; ++m)
                #pragma unroll
                for (int j = 0; j < 4; ++j)
                    acc[m][j] = __builtin_amdgcn_mfma_f32_16x16x32_bf16(af[m], bfr[j], acc[m][j], 0, 0, 0);
        }
        __syncthreads();
    }

    #pragma unroll
    for (int m = 0; m < 4; ++m) {
        const int ib = n0 + wi * 64 + m * 16 + (lane >> 4) * 4;
        #pragma unroll
        for (int j = 0; j < 4; ++j) {
            const int jb = d0 + wj * 64 + j * 16 + (lane & 15);
            f32x4 vv = acc[m][j];
            #pragma unroll
            for (int r = 0; r < 4; ++r) {
                float val = vv[r];
                if (act) val = (val > 0.f) ? (val + 1.f) : __expf(val);
                Tb[(size_t)(ib + r) * CD + jb] = f2b(val);
            }
        }
    }
}

// ---------- final GEMM: out[b][d][n] = sum_c Wp[d][c]*Tm[b][n][c] + bias[d] ----------
__global__ __launch_bounds__(256)
void gemm_final(const unsigned short* __restrict__ Wp, const unsigned short* __restrict__ Tm,
                float* __restrict__ out, const float* __restrict__ bias) {
    __shared__ __align__(16) unsigned short Asm[128 * 64];
    __shared__ __align__(16) unsigned short Bsm[128 * 64];
    const int nper = gridDim.x >> 3;
    const int work = (blockIdx.x & 7) * nper + (blockIdx.x >> 3);
    const int i0 = (work & 3) * 128;             // d tile (fastest -> shares Tm panel)
    const int j0 = ((work >> 2) & 31) * 128;     // token tile
    const int b  = work >> 7;
    const unsigned short* Bb = Tm + (size_t)b * NT * CD;
    const int tid  = threadIdx.x;
    const int lane = tid & 63;
    const int wv   = tid >> 6;
    const int wi = wv >> 1, wj = wv & 1;

    f32x4 acc[4][4];
    #pragma unroll
    for (int m = 0; m < 4; ++m)
        #pragma unroll
        for (int j = 0; j < 4; ++j)
            acc[m][j] = (f32x4){0.f, 0.f, 0.f, 0.f};

    for (int k0 = 0; k0 < CD; k0 += 64) {
        #pragma unroll
        for (int it = 0; it < 4; ++it) {
            const int idx = it * 256 + tid;
            const int r = idx >> 3, p = idx & 7;
            const int ps = p ^ (r & 7);
            gload_lds16(Wp + (size_t)(i0 + r) * CD + k0 + ps * 8, (char*)Asm + idx * 16);
            gload_lds16(Bb + (size_t)(j0 + r) * CD + k0 + ps * 8, (char*)Bsm + idx * 16);
        }
        __syncthreads();
        #pragma unroll
        for (int kk = 0; kk < 2; ++kk) {
            bf8 af[4], bfr[4];
            #pragma unroll
            for (int m = 0; m < 4; ++m) {
                const int r  = wi * 64 + m * 16 + (lane & 15);
                const int kp = kk * 4 + (lane >> 4);
                af[m] = *(const bf8*)((const char*)Asm + r * 128 + ((kp ^ (r & 7)) * 16));
            }
            #pragma unroll
            for (int j = 0; j < 4; ++j) {
                const int r  = wj * 64 + j * 16 + (lane & 15);
                const int kp = kk * 4 + (lane >> 4);
                bfr[j] = *(const bf8*)((const char*)Bsm + r * 128 + ((kp ^ (r & 7)) * 16));
            }
            #pragma unroll
            for (int m = 0; m < 4; ++m)
                #pragma unroll
                for (int j = 0; j < 4; ++j)
                    acc[m][j] = __builtin_amdgcn_mfma_f32_16x16x32_bf16(af[m], bfr[j], acc[m][j], 0, 0, 0);
        }
        __syncthreads();
    }

    #pragma unroll
    for (int m = 0; m < 4; ++m) {
        const int ib = i0 + wi * 64 + m * 16 + (lane >> 4) * 4;
        #pragma unroll
        for (int j = 0; j < 4; ++j) {
            const int jb = j0 + wj * 64 + j * 16 + (lane & 15);
            f32x4 v = acc[m][j];
            #pragma unroll
            for (int r = 0; r < 4; ++r)
                out[(size_t)b * CD * NT + (size_t)(ib + r) * NT + jb] = v[r] + bias[ib + r];
        }
    }
}

// ---------- Ksum[b][c] = sum_n K[b][n][c]  (2-pass, deterministic) ----------
__global__ __launch_bounds__(256)
void ksum_part(const unsigned short* __restrict__ K, float* __restrict__ part) {
    const int b = blockIdx.y, ch = blockIdx.x, t = threadIdx.x;
    const unsigned short* base = K + ((size_t)b * NT + ch * 256) * CD;
    float a0 = 0.f, a1 = 0.f;
    for (int nn = 0; nn < 256; ++nn) {
        a0 += b2f(base[(size_t)nn * CD + t]);
        a1 += b2f(base[(size_t)nn * CD + 256 + t]);
    }
    float* p = part + (size_t)(b * 16 + ch) * CD;
    p[t] = a0; p[256 + t] = a1;
}
__global__ __launch_bounds__(512)
void ksum_red(const float* __restrict__ part, float* __restrict__ Ks) {
    const int b = blockIdx.x, c = threadIdx.x;
    float s = 0.f;
    #pragma unroll
    for (int i = 0; i < 16; ++i) s += part[(size_t)(b * 16 + i) * CD + c];
    Ks[b * CD + c] = s;
}

// ---------- middle (MFMA, builtins only) ----------
__global__ __launch_bounds__(256)
void middle2(const unsigned short* __restrict__ Q, const unsigned short* __restrict__ K,
             const unsigned short* __restrict__ V, const float* __restrict__ Ksum,
             unsigned short* __restrict__ T) {
    __shared__ __align__(16) unsigned short sV[4][512];      // per-wave V token row
    __shared__ __align__(16) unsigned short sP[4][16][32];   // per-wave P^T [h][h'], h'=16..31 zero
    const int b = blockIdx.y;
    const int tid = threadIdx.x;
    const int w = tid >> 6, lane = tid & 63;
    const int r16 = lane & 15, g = lane >> 4;
    const int n0 = blockIdx.x * 16 + w * 4;
    const unsigned short* Qb = Q + ((size_t)b * NT + n0) * CD;
    const unsigned short* Kb = K + ((size_t)b * NT + n0) * CD;
    const unsigned short* Vb = V + ((size_t)b * NT + n0) * CD;
    unsigned short* Tb = T + ((size_t)b * NT + n0) * CD;
    const int fragoff = r16 * 32 + g * 8;   // head h=r16, d=g*8..g*8+7

    {
        const int r = lane >> 2, cq = lane & 3;
        *(u16x4*)&sP[w][r][16 + cq * 4] = (u16x4){0, 0, 0, 0};
    }

    const float* ksp = Ksum + b * CD + fragoff;
    float ks[8];
    {
        float4 a0 = *(const float4*)ksp;
        float4 a1 = *(const float4*)(ksp + 4);
        ks[0] = a0.x; ks[1] = a0.y; ks[2] = a0.z; ks[3] = a0.w;
        ks[4] = a1.x; ks[5] = a1.y; ks[6] = a1.z; ks[7] = a1.w;
    }
    unsigned short* sVw = &sV[w][0];

    for (int t = 0; t < 4; ++t) {
        asm volatile("s_waitcnt lgkmcnt(0)" ::: "memory");
        __builtin_amdgcn_sched_barrier(0);
        gload_lds16(Vb + (size_t)t * CD + lane * 8, (char*)sVw + lane * 16);

        const bf8 qf = *(const bf8*)(Qb + (size_t)t * CD + fragoff);
        const bf8 kf = *(const bf8*)(Kb + (size_t)t * CD + fragoff);

        f32x4 s = {0.f, 0.f, 0.f, 0.f};
        s = __builtin_amdgcn_mfma_f32_16x16x32_bf16(kf, qf, s, 0, 0, 0);

        float part = 0.f;
        #pragma unroll
        for (int e = 0; e < 8; ++e) part += b2f((unsigned short)qf[e]) * ks[e];
        part += __shfl_xor(part, 16, 64);
        part += __shfl_xor(part, 32, 64);
        const float z = 1.f / (part + EPSV);

        u16x4 pw;
        #pragma unroll
        for (int r = 0; r < 4; ++r) pw[r] = f2b(s[r] * z);
        *(u16x4*)&sP[w][r16][g * 4] = pw;

        asm volatile("s_waitcnt vmcnt(0) lgkmcnt(0)" ::: "memory");
        __builtin_amdgcn_sched_barrier(0);

        const bf8 pb = *(const bf8*)&sP[w][r16][g * 8];
        bf8 va0 = {}, va1 = {};
        if (g < 2) {
            #pragma unroll
            for (int e = 0; e < 8; ++e) {
                va0[e] = (short)sVw[(g * 8 + e) * 32 + r16];
                va1[e] = (short)sVw[(g * 8 + e) * 32 + 16 + r16];
            }
        }

        f32x4 o0 = {0.f, 0.f, 0.f, 0.f}, o1 = {0.f, 0.f, 0.f, 0.f};
        o0 = __builtin_amdgcn_mfma_f32_16x16x32_bf16(va0, pb, o0, 0, 0, 0);
        o1 = __builtin_amdgcn_mfma_f32_16x16x32_bf16(va1, pb, o1, 0, 0, 0);

        u16x4 w0, w1;
        #pragma unroll
        for (int r = 0; r < 4; ++r) { w0[r] = f2b(o0[r]); w1[r] = f2b(o1[r]); }
        *(u16x4*)(Tb + (size_t)t * CD + r16 * 32 + g * 4)      = w0;
        *(u16x4*)(Tb + (size_t)t * CD + r16 * 32 + 16 + g * 4) = w1;
    }
}

// ---------- launch ----------
extern "C" void kernel_launch(void* const* d_in, const int* in_sizes, int n_in,
                              void* d_out, int out_size, void* d_ws, size_t ws_size,
                              hipStream_t stream) {
    const float* q  = (const float*)d_in[0];
    const float* k  = (const float*)d_in[1];
    const float* v  = (const float*)d_in[2];
    const float* Wq = (const float*)d_in[3];
    const float* Wk = (const float*)d_in[4];
    const float* Wv = (const float*)d_in[5];
    const float* Wp = (const float*)d_in[6];
    const float* bp = (const float*)d_in[7];
    float* out = (float*)d_out;

    const size_t slab = (size_t)BATCH * NT * CD;
    unsigned short* Qp = (unsigned short*)d_ws;
    unsigned short* Kp = Qp + slab;
    unsigned short* Vp = Kp + slab;
    unsigned short* Tm = Vp + slab;
    unsigned short* Wb = Tm + slab;
    float* Kpart = (float*)(Wb + 4 * (size_t)CD * CD);
    float* Ks    = Kpart + 8 * 16 * CD;

    wconv<<<dim3(64, 4), 256, 0, stream>>>(Wq, Wk, Wv, Wp, Wb);

    const unsigned short* Wpb = Wb + (size_t)3 * CD * CD;

    proj_gemm_all<<<3072, 256, 0, stream>>>(q, k, v, Wb, Qp, Kp, Vp);

    ksum_part<<<dim3(16, 8), 256, 0, stream>>>(Kp, Kpart);
    ksum_red <<<dim3(8),     512, 0, stream>>>(Kpart, Ks);

    middle2<<<dim3(256, 8), 256, 0, stream>>>(Qp, Kp, Vp, Ks, Tm);

    gemm_final<<<1024, 256, 0, stream>>>(Wpb, Tm, out, bp);
}

// Round 9
// 193.681 us; speedup vs baseline: 1.4985x; 1.1830x over previous
//
#include <hip/hip_runtime.h>
#include <hip/hip_bf16.h>

#define BATCH 8
#define CD 512
#define NT 4096
#define EPSV 1e-5f

using u16x8 = __attribute__((ext_vector_type(8))) unsigned short;
using u16x4 = __attribute__((ext_vector_type(4))) unsigned short;
using bf8   = __attribute__((ext_vector_type(8))) short;
using f32x4 = __attribute__((ext_vector_type(4))) float;

__device__ __forceinline__ float b2f(unsigned short u) {
    union { unsigned int i; float f; } x; x.i = ((unsigned int)u) << 16; return x.f;
}
__device__ __forceinline__ unsigned short f2b(float f) {
    unsigned int x = __float_as_uint(f);
    unsigned int r = (x + 0x7fffu + ((x >> 16) & 1u)) >> 16;
    return (unsigned short)r;
}
__device__ __forceinline__ unsigned int cvtpk(float a, float b) {
    unsigned int r;
    asm("v_cvt_pk_bf16_f32 %0, %1, %2" : "=v"(r) : "v"(a), "v"(b));
    return r;  // lo = bf16(a), hi = bf16(b)
}
__device__ __forceinline__ void gload_lds16(const void* g, void* l) {
    __builtin_amdgcn_global_load_lds((const __attribute__((address_space(1))) unsigned int*)g,
                                     (__attribute__((address_space(3))) unsigned int*)l, 16, 0, 0);
}
__device__ __forceinline__ int swz8(int r) { return (r ^ (r >> 3)) & 7; }

// ---------- W fp32 -> bf16 (row-major kept) ----------
__global__ __launch_bounds__(256)
void wconv(const float* __restrict__ W0, const float* __restrict__ W1,
           const float* __restrict__ W2, const float* __restrict__ W3,
           unsigned short* __restrict__ Wb) {
    const float* src = (blockIdx.y == 0) ? W0 : (blockIdx.y == 1) ? W1 : (blockIdx.y == 2) ? W2 : W3;
    unsigned short* dst = Wb + (size_t)blockIdx.y * CD * CD;
    const int base = blockIdx.x * 4096 + threadIdx.x * 16;
    u16x8 o0, o1;
    #pragma unroll
    for (int i = 0; i < 4; ++i) {
        float4 v = *reinterpret_cast<const float4*>(src + base + i * 4);
        unsigned short* t = (i < 2) ? (unsigned short*)&o0 : (unsigned short*)&o1;
        t[(i & 1) * 4 + 0] = f2b(v.x); t[(i & 1) * 4 + 1] = f2b(v.y);
        t[(i & 1) * 4 + 2] = f2b(v.z); t[(i & 1) * 4 + 3] = f2b(v.w);
    }
    *(u16x8*)(dst + base)     = o0;
    *(u16x8*)(dst + base + 8) = o1;
}

// ---------- projection GEMM: block = 64 tokens x FULL 512 d ----------
// T[b][n][d] = act( sum_c X[b][c][n] * W[d][c] ).  X^T tile staged ONCE (64KB LDS,
// swz8 both sides); W (16KB) re-staged per (d-tile, k-chunk) via global_load_lds.
// mat==1 (K) also reduces elu(K)+1 over the 64 tokens into Kpart (folded ksum).
__global__ __launch_bounds__(256)
void proj_gemm_all(const float* __restrict__ q, const float* __restrict__ k,
                   const float* __restrict__ v, const unsigned short* __restrict__ Wb,
                   unsigned short* __restrict__ Qp, unsigned short* __restrict__ Kp,
                   unsigned short* __restrict__ Vp, float* __restrict__ Kpart) {
    __shared__ __align__(16) unsigned short Xs[64 * 512];   // 64KB [tok][c] swizzled
    __shared__ __align__(16) unsigned short Ws[128 * 64];   // 16KB [d][c] swizzled
    const int nper = gridDim.x >> 3;                        // 192
    const int work = (blockIdx.x & 7) * nper + (blockIdx.x >> 3);
    const int mat  = work / 512;                            // 0..2
    const int rem  = work - mat * 512;
    const int b    = rem >> 6;
    const int tile = rem & 63;
    const int n0   = tile * 64;
    const float* Xb = (mat == 0 ? q : mat == 1 ? k : v) + (size_t)b * CD * NT;
    const unsigned short* W = Wb + (size_t)mat * CD * CD;
    unsigned short* Tb = (mat == 0 ? Qp : mat == 1 ? Kp : Vp) + (size_t)b * NT * CD;
    const int act = (mat < 2);

    const int tid = threadIdx.x, lane = tid & 63, wv = tid >> 6;

    // ---- stage X^T tile once: 64 tok x 512 c (f32 -> bf16, transposed in regs) ----
    #pragma unroll 4
    for (int i = 0; i < 8; ++i) {
        const int s  = i * 256 + tid;            // micro-tile id (4c x 4tok)
        const int c0 = (s >> 4) * 4;
        const int t0 = (s & 15) * 4;
        const float* p = Xb + (size_t)c0 * NT + n0 + t0;
        float4 r0 = *(const float4*)(p);
        float4 r1 = *(const float4*)(p + NT);
        float4 r2 = *(const float4*)(p + 2 * NT);
        float4 r3 = *(const float4*)(p + 3 * NT);
        float a0[4] = {r0.x, r0.y, r0.z, r0.w};
        float a1[4] = {r1.x, r1.y, r1.z, r1.w};
        float a2[4] = {r2.x, r2.y, r2.z, r2.w};
        float a3[4] = {r3.x, r3.y, r3.z, r3.w};
        #pragma unroll
        for (int j = 0; j < 4; ++j) {
            uint2 u;
            u.x = cvtpk(a0[j], a1[j]);           // c0, c0+1
            u.y = cvtpk(a2[j], a3[j]);           // c0+2, c0+3
            const int row  = t0 + j;
            const int byte = (row * 1024 + c0 * 2) ^ (swz8(row) << 4);
            *(uint2*)((char*)Xs + byte) = u;
        }
    }
    __syncthreads();

    for (int d0i = 0; d0i < 4; ++d0i) {
        f32x4 acc[4][2];
        #pragma unroll
        for (int m = 0; m < 4; ++m)
            #pragma unroll
            for (int j = 0; j < 2; ++j)
                acc[m][j] = (f32x4){0.f, 0.f, 0.f, 0.f};

        for (int kc = 0; kc < 8; ++kc) {
            #pragma unroll
            for (int it = 0; it < 4; ++it) {
                const int idx = it * 256 + tid;
                const int r = idx >> 3, p = idx & 7;
                gload_lds16(W + (size_t)(d0i * 128 + r) * CD + kc * 64 + (p ^ swz8(r)) * 8,
                            (char*)Ws + idx * 16);
            }
            __syncthreads();
            #pragma unroll
            for (int kk = 0; kk < 2; ++kk) {
                const int kp = kk * 4 + (lane >> 4);
                bf8 af[4], bfr[2];
                #pragma unroll
                for (int m = 0; m < 4; ++m) {
                    const int r = m * 16 + (lane & 15);
                    af[m] = *(const bf8*)((const char*)Xs +
                            ((r * 1024 + kc * 128 + kp * 16) ^ (swz8(r) << 4)));
                }
                #pragma unroll
                for (int j = 0; j < 2; ++j) {
                    const int rw = wv * 32 + j * 16 + (lane & 15);
                    bfr[j] = *(const bf8*)((const char*)Ws + rw * 128 + ((kp ^ swz8(rw)) * 16));
                }
                #pragma unroll
                for (int m = 0; m < 4; ++m)
                    #pragma unroll
                    for (int j = 0; j < 2; ++j)
                        acc[m][j] = __builtin_amdgcn_mfma_f32_16x16x32_bf16(af[m], bfr[j], acc[m][j], 0, 0, 0);
            }
            __syncthreads();
        }

        // epilogue for this 128-d tile (+ folded K-sum over the 64 tokens)
        float kacc[2] = {0.f, 0.f};
        #pragma unroll
        for (int m = 0; m < 4; ++m) {
            const int ib = n0 + m * 16 + ((lane >> 4) << 2);
            #pragma unroll
            for (int j = 0; j < 2; ++j) {
                const int jb = d0i * 128 + wv * 32 + j * 16 + (lane & 15);
                f32x4 vv = acc[m][j];
                #pragma unroll
                for (int r = 0; r < 4; ++r) {
                    float val = vv[r];
                    if (act) val = (val > 0.f) ? (val + 1.f) : __expf(val);
                    if (mat == 1) kacc[j] += val;
                    Tb[(size_t)(ib + r) * CD + jb] = f2b(val);
                }
            }
        }
        if (mat == 1) {
            #pragma unroll
            for (int j = 0; j < 2; ++j) {
                float s = kacc[j];
                s += __shfl_xor(s, 16, 64);
                s += __shfl_xor(s, 32, 64);
                if (lane < 16) {
                    const int jb = d0i * 128 + wv * 32 + j * 16 + lane;
                    Kpart[(size_t)(b * 64 + tile) * CD + jb] = s;
                }
            }
        }
    }
}

// ---------- Ks[b][c] = sum over 64 token-tiles of Kpart ----------
__global__ __launch_bounds__(512)
void ksum_red2(const float* __restrict__ Kpart, float* __restrict__ Ks) {
    const int b = blockIdx.x, c = threadIdx.x;
    float s = 0.f;
    #pragma unroll 8
    for (int t = 0; t < 64; ++t) s += Kpart[(size_t)(b * 64 + t) * CD + c];
    Ks[b * CD + c] = s;
}

// ---------- final GEMM: out[b][d][n] = sum_c Wp[d][c]*Tm[b][n][c] + bias[d] ----------
__global__ __launch_bounds__(256)
void gemm_final(const unsigned short* __restrict__ Wp, const unsigned short* __restrict__ Tm,
                float* __restrict__ out, const float* __restrict__ bias) {
    __shared__ __align__(16) unsigned short Asm[128 * 64];
    __shared__ __align__(16) unsigned short Bsm[128 * 64];
    const int nper = gridDim.x >> 3;
    const int work = (blockIdx.x & 7) * nper + (blockIdx.x >> 3);
    const int i0 = (work & 3) * 128;             // d tile (fastest -> shares Tm panel)
    const int j0 = ((work >> 2) & 31) * 128;     // token tile
    const int b  = work >> 7;
    const unsigned short* Bb = Tm + (size_t)b * NT * CD;
    const int tid  = threadIdx.x;
    const int lane = tid & 63;
    const int wv   = tid >> 6;
    const int wi = wv >> 1, wj = wv & 1;

    f32x4 acc[4][4];
    #pragma unroll
    for (int m = 0; m < 4; ++m)
        #pragma unroll
        for (int j = 0; j < 4; ++j)
            acc[m][j] = (f32x4){0.f, 0.f, 0.f, 0.f};

    for (int k0 = 0; k0 < CD; k0 += 64) {
        #pragma unroll
        for (int it = 0; it < 4; ++it) {
            const int idx = it * 256 + tid;
            const int r = idx >> 3, p = idx & 7;
            const int ps = p ^ (r & 7);
            gload_lds16(Wp + (size_t)(i0 + r) * CD + k0 + ps * 8, (char*)Asm + idx * 16);
            gload_lds16(Bb + (size_t)(j0 + r) * CD + k0 + ps * 8, (char*)Bsm + idx * 16);
        }
        __syncthreads();
        #pragma unroll
        for (int kk = 0; kk < 2; ++kk) {
            bf8 af[4], bfr[4];
            #pragma unroll
            for (int m = 0; m < 4; ++m) {
                const int r  = wi * 64 + m * 16 + (lane & 15);
                const int kp = kk * 4 + (lane >> 4);
                af[m] = *(const bf8*)((const char*)Asm + r * 128 + ((kp ^ (r & 7)) * 16));
            }
            #pragma unroll
            for (int j = 0; j < 4; ++j) {
                const int r  = wj * 64 + j * 16 + (lane & 15);
                const int kp = kk * 4 + (lane >> 4);
                bfr[j] = *(const bf8*)((const char*)Bsm + r * 128 + ((kp ^ (r & 7)) * 16));
            }
            #pragma unroll
            for (int m = 0; m < 4; ++m)
                #pragma unroll
                for (int j = 0; j < 4; ++j)
                    acc[m][j] = __builtin_amdgcn_mfma_f32_16x16x32_bf16(af[m], bfr[j], acc[m][j], 0, 0, 0);
        }
        __syncthreads();
    }

    #pragma unroll
    for (int m = 0; m < 4; ++m) {
        const int ib = i0 + wi * 64 + m * 16 + (lane >> 4) * 4;
        #pragma unroll
        for (int j = 0; j < 4; ++j) {
            const int jb = j0 + wj * 64 + j * 16 + (lane & 15);
            f32x4 v = acc[m][j];
            #pragma unroll
            for (int r = 0; r < 4; ++r)
                out[(size_t)b * CD * NT + (size_t)(ib + r) * NT + jb] = v[r] + bias[ib + r];
        }
    }
}

// ---------- middle (MFMA, builtins only) ----------
__global__ __launch_bounds__(256)
void middle2(const unsigned short* __restrict__ Q, const unsigned short* __restrict__ K,
             const unsigned short* __restrict__ V, const float* __restrict__ Ksum,
             unsigned short* __restrict__ T) {
    __shared__ __align__(16) unsigned short sV[4][512];      // per-wave V token row
    __shared__ __align__(16) unsigned short sP[4][16][32];   // per-wave P^T [h][h'], h'=16..31 zero
    const int b = blockIdx.y;
    const int tid = threadIdx.x;
    const int w = tid >> 6, lane = tid & 63;
    const int r16 = lane & 15, g = lane >> 4;
    const int n0 = blockIdx.x * 16 + w * 4;
    const unsigned short* Qb = Q + ((size_t)b * NT + n0) * CD;
    const unsigned short* Kb = K + ((size_t)b * NT + n0) * CD;
    const unsigned short* Vb = V + ((size_t)b * NT + n0) * CD;
    unsigned short* Tb = T + ((size_t)b * NT + n0) * CD;
    const int fragoff = r16 * 32 + g * 8;   // head h=r16, d=g*8..g*8+7

    {
        const int r = lane >> 2, cq = lane & 3;
        *(u16x4*)&sP[w][r][16 + cq * 4] = (u16x4){0, 0, 0, 0};
    }

    const float* ksp = Ksum + b * CD + fragoff;
    float ks[8];
    {
        float4 a0 = *(const float4*)ksp;
        float4 a1 = *(const float4*)(ksp + 4);
        ks[0] = a0.x; ks[1] = a0.y; ks[2] = a0.z; ks[3] = a0.w;
        ks[4] = a1.x; ks[5] = a1.y; ks[6] = a1.z; ks[7] = a1.w;
    }
    unsigned short* sVw = &sV[w][0];

    for (int t = 0; t < 4; ++t) {
        asm volatile("s_waitcnt lgkmcnt(0)" ::: "memory");
        __builtin_amdgcn_sched_barrier(0);
        gload_lds16(Vb + (size_t)t * CD + lane * 8, (char*)sVw + lane * 16);

        const bf8 qf = *(const bf8*)(Qb + (size_t)t * CD + fragoff);
        const bf8 kf = *(const bf8*)(Kb + (size_t)t * CD + fragoff);

        f32x4 s = {0.f, 0.f, 0.f, 0.f};
        s = __builtin_amdgcn_mfma_f32_16x16x32_bf16(kf, qf, s, 0, 0, 0);

        float part = 0.f;
        #pragma unroll
        for (int e = 0; e < 8; ++e) part += b2f((unsigned short)qf[e]) * ks[e];
        part += __shfl_xor(part, 16, 64);
        part += __shfl_xor(part, 32, 64);
        const float z = 1.f / (part + EPSV);

        u16x4 pw;
        #pragma unroll
        for (int r = 0; r < 4; ++r) pw[r] = f2b(s[r] * z);
        *(u16x4*)&sP[w][r16][g * 4] = pw;

        asm volatile("s_waitcnt vmcnt(0) lgkmcnt(0)" ::: "memory");
        __builtin_amdgcn_sched_barrier(0);

        const bf8 pb = *(const bf8*)&sP[w][r16][g * 8];
        bf8 va0 = {}, va1 = {};
        if (g < 2) {
            #pragma unroll
            for (int e = 0; e < 8; ++e) {
                va0[e] = (short)sVw[(g * 8 + e) * 32 + r16];
                va1[e] = (short)sVw[(g * 8 + e) * 32 + 16 + r16];
            }
        }

        f32x4 o0 = {0.f, 0.f, 0.f, 0.f}, o1 = {0.f, 0.f, 0.f, 0.f};
        o0 = __builtin_amdgcn_mfma_f32_16x16x32_bf16(va0, pb, o0, 0, 0, 0);
        o1 = __builtin_amdgcn_mfma_f32_16x16x32_bf16(va1, pb, o1, 0, 0, 0);

        u16x4 w0, w1;
        #pragma unroll
        for (int r = 0; r < 4; ++r) { w0[r] = f2b(o0[r]); w1[r] = f2b(o1[r]); }
        *(u16x4*)(Tb + (size_t)t * CD + r16 * 32 + g * 4)      = w0;
        *(u16x4*)(Tb + (size_t)t * CD + r16 * 32 + 16 + g * 4) = w1;
    }
}

// ---------- launch ----------
extern "C" void kernel_launch(void* const* d_in, const int* in_sizes, int n_in,
                              void* d_out, int out_size, void* d_ws, size_t ws_size,
                              hipStream_t stream) {
    const float* q  = (const float*)d_in[0];
    const float* k  = (const float*)d_in[1];
    const float* v  = (const float*)d_in[2];
    const float* Wq = (const float*)d_in[3];
    const float* Wk = (const float*)d_in[4];
    const float* Wv = (const float*)d_in[5];
    const float* Wp = (const float*)d_in[6];
    const float* bp = (const float*)d_in[7];
    float* out = (float*)d_out;

    const size_t slab = (size_t)BATCH * NT * CD;
    unsigned short* Qp = (unsigned short*)d_ws;
    unsigned short* Kp = Qp + slab;
    unsigned short* Vp = Kp + slab;
    unsigned short* Tm = Vp + slab;
    unsigned short* Wb = Tm + slab;
    float* Kpart = (float*)(Wb + 4 * (size_t)CD * CD);   // 512 tiles x 512 f32 = 1MB
    float* Ks    = Kpart + (size_t)512 * CD;

    wconv<<<dim3(64, 4), 256, 0, stream>>>(Wq, Wk, Wv, Wp, Wb);

    const unsigned short* Wpb = Wb + (size_t)3 * CD * CD;

    proj_gemm_all<<<1536, 256, 0, stream>>>(q, k, v, Wb, Qp, Kp, Vp, Kpart);

    ksum_red2<<<8, 512, 0, stream>>>(Kpart, Ks);

    middle2<<<dim3(256, 8), 256, 0, stream>>>(Qp, Kp, Vp, Ks, Tm);

    gemm_final<<<1024, 256, 0, stream>>>(Wpb, Tm, out, bp);
}